// Round 3
// baseline (510.998 us; speedup 1.0000x reference)
//
#include <hip/hip_runtime.h>
#include <math.h>

#define BB 16
#define NN 512
#define HID 32

#define HALO 16
#define TW 96        // logical tile width (64 + 2*HALO)
#define TWP 97       // LDS pitch: 97 % 32 == 1 -> conflict-free Phase D
#define OT 64

// fast tanh-approx GELU: gelu(v) = v / (1 + exp2(K1*v + K2*v^3))
#define GELU_K1 (-2.302208201f)
#define GELU_K2 (-0.102944244f)

// LFA angle step 2*pi/513 and its cos/sin
#define TPH 0.012247925f
#define CDR 0.99992499f
#define SDR 0.012247618f

// ---------------------------------------------------------------------------
// One full cycle: 10 Jacobi sweeps (register-resident 12x3 blocks, LDS halo
// exchange only) + fused pointwise-MLP correction (thread-remapped, 1x work)
// Guard-ring LDS tile: logical (row,col) in [-1,96]^2, physically in-bounds;
// guards zeroed once -> NO clamps, and every LDS access is one base pointer
// + compile-time immediate. Proven config: 128 VGPR, 4 waves/SIMD.
// DO NOT add live state near Phase C/D: several attempts tipped to 132 VGPR
// (+20..50 us/cycle). DO NOT use __launch_bounds__(256,4): round-1 measured
// the backend targets the 64-VGPR bucket and spills (FETCH 39->391 MB).
// Round-2 measured: a pre-Phase-A inline-LFA block tips FIRST to 132 VGPR
// (113.7 -> ~135 us) -> LFA is now NEVER materialized. Phase D computes its
// 16 LFA values in-register (2 sincos + 2-fma rotation, bit-identical to the
// old lfa_kernel group-of-4 scheme) in the low-pressure post-sweep region.
// FIRST: x0 = 0, sweep 0 collapses to cur = mask*(tau*f); tile fill skipped;
//        zeroes the accumulator/counter slots.
// RES:   cycle-3 variant. No x store. r_final = r_pre - A(H) via an H-ring
//        exchange through the LDS tile (ring cells are bit-exact
//        recomputations: contamination depth after 10 sweeps is 10 < 15).
//        Block-reduces sum(r^2), sum(f^2) into accp; the LAST block computes
//        the final norm ratio (device-scope counter) -> no finalize dispatch.
// ---------------------------------------------------------------------------
template <bool FIRST, bool RES>
__global__ __launch_bounds__(256) void fused_cycle(
        const float* __restrict__ xin, float* __restrict__ xout,
        const float* __restrict__ f, const float* __restrict__ kernelA,
        const float* __restrict__ W1, const float* __restrict__ b1,
        const float* __restrict__ W2, const float* __restrict__ b2,
        float* __restrict__ accp, float* __restrict__ outp) {
    __shared__ float sxraw[98 * TWP + 2];
    float* sx = sxraw + TWP + 1;   // logical origin (0,0); row r col c -> sx[r*TWP+c]
    const int tx = threadIdx.x;   // 0..31
    const int ty = threadIdx.y;   // 0..7
    const int t  = ty * 32 + tx;
    const int b  = blockIdx.z;
    const int gy0 = blockIdx.y * OT;
    const int gx0 = blockIdx.x * OT;
    const int goi = gy0 - HALO;
    const int goj = gx0 - HALO;
    const float* fg = f + (size_t)b * NN * NN;
    const float* ag = kernelA + b * 9;   // uniform -> s_load
    const float ar0 = ag[0], ar1 = ag[1], ar2 = ag[2], ar3 = ag[3], ar4 = ag[4];
    const float ar5 = ag[5], ar6 = ag[6], ar7 = ag[7], ar8 = ag[8];
    const float tau = 0.5f / ar4;
    // tau-scaled stencil for the sweeps
    const float s0 = tau * ar0, q1 = tau * ar1, q2 = tau * ar2, q3 = tau * ar3;
    const float q4 = tau * ar4, q5 = tau * ar5, q6 = tau * ar6, q7 = tau * ar7;
    const float q8 = tau * ar8;
    // LFA symbol sums (uniform -> SGPR, free)
    const float A35 = ar3 + ar5, A17 = ar1 + ar7, A08 = ar0 + ar8, A26 = ar2 + ar6;
    const float B53 = ar5 - ar3, B71 = ar7 - ar1, B80 = ar8 - ar0, B26 = ar2 - ar6;

    if (FIRST) {
        // zero norm accumulators + done-counter (replaces hipMemsetAsync;
        // stream order puts this before cycle-3's atomics)
        if (t == 0 && (blockIdx.x | blockIdx.y | blockIdx.z) == 0) {
            accp[0] = 0.f;
            accp[1] = 0.f;
            ((unsigned int*)accp)[2] = 0u;
        }
    }

    // ---- zero the guard ring (top band, shared L/R col guards, bottom band)
    if (t < 98) sxraw[t] = 0.f;                 // logical row -1, col -1..96
    if (t < 96) sxraw[97 + 97 * t] = 0.f;       // col -1 of row t (== col 96 of row t-1)
    if (t < 98) sxraw[9409 + t] = 0.f;          // logical row 96, col -1..96

    // ---- Phase A: tile -> LDS (interior 96x96); skipped for FIRST ----
    if (!FIRST) {
        const float* xg = xin + (size_t)b * NN * NN;
#pragma unroll
        for (int k = 0; k < (TW * TW) / 256; ++k) {
            int idx = t + k * 256;
            int row = idx / TW, col = idx - row * TW;
            int gi = goi + row, gj = goj + col;
            float v = 0.f;
            if (gi >= 0 && gi < NN && gj >= 0 && gj < NN) v = xg[gi * NN + gj];
            sx[row * TWP + col] = v;
        }
    }

    const int R0 = ty * 12, C0 = tx * 3;

    // single base pointers: all LDS traffic below is base + compile-time imm
    const float* pb  = sx + (R0 - 1) * TWP + (C0 - 1);  // extended-block origin
    float*       pwv = sx + R0 * TWP + C0;              // owned-cell origin

    // masks: cell updates only if tile-interior AND inside global domain
    float vR[12], vC[3];
#pragma unroll
    for (int r = 0; r < 12; ++r) {
        int R = R0 + r, gi = goi + R;
        vR[r] = (R >= 1 && R < TW - 1 && gi >= 0 && gi < NN) ? 1.f : 0.f;
    }
#pragma unroll
    for (int c = 0; c < 3; ++c) {
        int C = C0 + c, gj = goj + C;
        vC[c] = (C >= 1 && C < TW - 1 && gj >= 0 && gj < NN) ? 1.f : 0.f;
    }

    // tau-scaled f for owned cells (0 outside domain)
    float frt[12][3];
#pragma unroll
    for (int r = 0; r < 12; ++r) {
        int gi = goi + R0 + r;
#pragma unroll
        for (int c = 0; c < 3; ++c) {
            int gj = goj + C0 + c;
            frt[r][c] = (gi >= 0 && gi < NN && gj >= 0 && gj < NN)
                            ? tau * fg[gi * NN + gj] : 0.f;
        }
    }

    __syncthreads();   // tile + guards visible

    // ---- Phase B: own cells -> registers ----
    float cur[12][3];
    if (FIRST) {
        // collapsed sweep 0: x1 = mask * (tau*f); publish borders
#pragma unroll
        for (int r = 0; r < 12; ++r) {
#pragma unroll
            for (int c = 0; c < 3; ++c)
                cur[r][c] = (vR[r] * vC[c]) * frt[r][c];
        }
        pwv[0] = cur[0][0]; pwv[1] = cur[0][1]; pwv[2] = cur[0][2];
        pwv[11 * TWP] = cur[11][0]; pwv[11 * TWP + 1] = cur[11][1];
        pwv[11 * TWP + 2] = cur[11][2];
#pragma unroll
        for (int r = 1; r < 11; ++r) {
            pwv[r * TWP] = cur[r][0];
            pwv[r * TWP + 2] = cur[r][2];
        }
        __syncthreads();   // sweep-0 borders visible
    } else {
#pragma unroll
        for (int r = 0; r < 12; ++r) {
            cur[r][0] = pwv[r * TWP];
            cur[r][1] = pwv[r * TWP + 1];
            cur[r][2] = pwv[r * TWP + 2];
        }
    }

    // ---- Phase C: sweeps (FIRST starts at s=1: sweep 0 was collapsed) ----
    for (int s = FIRST ? 1 : 0; s < 10; ++s) {
        // halo reads (34), all immediate offsets off pb
        float top0 = pb[0], top1 = pb[1], top2 = pb[2], top3 = pb[3], top4 = pb[4];
        float bot0 = pb[13 * TWP],     bot1 = pb[13 * TWP + 1],
              bot2 = pb[13 * TWP + 2], bot3 = pb[13 * TWP + 3],
              bot4 = pb[13 * TWP + 4];
        float pm0 = top1, pm1v = top2, pm2 = top3;
        float Lm1 = top0, Rm1 = top4;
        float Lc = pb[TWP], Rc = pb[TWP + 4];
#pragma unroll
        for (int r = 0; r < 12; ++r) {
            float n0, n1, n2, Lp, Rp;
            if (r < 11) {
                n0 = cur[r + 1][0]; n1 = cur[r + 1][1]; n2 = cur[r + 1][2];
                Lp = pb[(r + 2) * TWP];
                Rp = pb[(r + 2) * TWP + 4];
            } else {
                n0 = bot1; n1 = bot2; n2 = bot3; Lp = bot0; Rp = bot4;
            }
            float o0 = cur[r][0], o1 = cur[r][1], o2 = cur[r][2];
            // c = 0
            {
                float ax = s0 * Lm1;
                ax = fmaf(q1, pm0, ax); ax = fmaf(q2, pm1v, ax);
                ax = fmaf(q3, Lc, ax);  ax = fmaf(q4, o0, ax);
                ax = fmaf(q5, o1, ax);  ax = fmaf(q6, Lp, ax);
                ax = fmaf(q7, n0, ax);  ax = fmaf(q8, n1, ax);
                cur[r][0] = fmaf(vR[r] * vC[0], frt[r][0] - ax, o0);
            }
            // c = 1
            {
                float ax = s0 * pm0;
                ax = fmaf(q1, pm1v, ax); ax = fmaf(q2, pm2, ax);
                ax = fmaf(q3, o0, ax);   ax = fmaf(q4, o1, ax);
                ax = fmaf(q5, o2, ax);   ax = fmaf(q6, n0, ax);
                ax = fmaf(q7, n1, ax);   ax = fmaf(q8, n2, ax);
                cur[r][1] = fmaf(vR[r] * vC[1], frt[r][1] - ax, o1);
            }
            // c = 2
            {
                float ax = s0 * pm1v;
                ax = fmaf(q1, pm2, ax); ax = fmaf(q2, Rm1, ax);
                ax = fmaf(q3, o1, ax);  ax = fmaf(q4, o2, ax);
                ax = fmaf(q5, Rc, ax);  ax = fmaf(q6, n1, ax);
                ax = fmaf(q7, n2, ax);  ax = fmaf(q8, Rp, ax);
                cur[r][2] = fmaf(vR[r] * vC[2], frt[r][2] - ax, o2);
            }
            pm0 = o0; pm1v = o1; pm2 = o2;
            Lm1 = Lc; Rm1 = Rc; Lc = Lp; Rc = Rp;
        }
        __syncthreads();   // all halo reads done
        if (s < 9) {
            // write border cells (26)
            pwv[0] = cur[0][0]; pwv[1] = cur[0][1]; pwv[2] = cur[0][2];
            pwv[11 * TWP] = cur[11][0]; pwv[11 * TWP + 1] = cur[11][1];
            pwv[11 * TWP + 2] = cur[11][2];
#pragma unroll
            for (int r = 1; r < 11; ++r) {
                pwv[r * TWP] = cur[r][0];
                pwv[r * TWP + 2] = cur[r][2];
            }
        } else {
            // final sweep: publish ALL cells for the correction phase
#pragma unroll
            for (int r = 0; r < 12; ++r) {
                pwv[r * TWP] = cur[r][0];
                pwv[r * TWP + 1] = cur[r][1];
                pwv[r * TWP + 2] = cur[r][2];
            }
        }
        __syncthreads();   // writes visible
    }

    // ---- Phase D: remapped correction, exactly 1x MLP work ----
    // thread t -> output row orow = t/4 (0..63), column segment oseg = t%4
    // Pitch 97: bank = orow + 16*oseg + k + const (mod 32) -> 2 lanes/bank (free).
    const int orow = t >> 2;
    const int oseg = t & 3;
    const int Rl = HALO + orow;           // 16..79
    const int Cl0 = HALO + oseg * 16;     // 16,32,48,64
    const float* pw = sx + (Rl - 1) * TWP + (Cl0 - 1);   // single base + imm
    const int gi = gy0 + orow;
    const int gjb = gx0 + oseg * 16;
    const float b2v = b2[0];

    if (!RES) {
        // ---- correction + x store. Order keeps peak pressure low:
        // w loads (54) -> fv -> rv (w0,w2,fv die) -> lv in-register -> MLP.
        float w0[18], w1[18], w2[18];
#pragma unroll
        for (int k = 0; k < 18; ++k) {
            w0[k] = pw[k];
            w1[k] = pw[TWP + k];
            w2[k] = pw[2 * TWP + k];
        }
        float rv[16];
        {
            const float4* f4 = (const float4*)(fg + (size_t)gi * NN + gjb);
            float fv[16];
#pragma unroll
            for (int q = 0; q < 4; ++q) {
                float4 fq = f4[q];
                fv[q * 4] = fq.x; fv[q * 4 + 1] = fq.y;
                fv[q * 4 + 2] = fq.z; fv[q * 4 + 3] = fq.w;
            }
#pragma unroll
            for (int k = 0; k < 16; ++k) {
                float ax = ar0 * w0[k];
                ax = fmaf(ar1, w0[k + 1], ax); ax = fmaf(ar2, w0[k + 2], ax);
                ax = fmaf(ar3, w1[k], ax);     ax = fmaf(ar4, w1[k + 1], ax);
                ax = fmaf(ar5, w1[k + 2], ax); ax = fmaf(ar6, w2[k], ax);
                ax = fmaf(ar7, w2[k + 1], ax); ax = fmaf(ar8, w2[k + 2], ax);
                rv[k] = fv[k] - ax;
            }
        }
        // lv in-register (bit-identical to old lfa_kernel: fresh sincos per
        // 4-col group + 2-fma rotation within the group)
        float lv[16];
        {
            float th2 = TPH * (float)(gi - NN / 2);
            float s2v, c2v;
            sincosf(th2, &s2v, &c2v);
            for (int g = 0; g < 4; ++g) {
                float th1 = TPH * (float)(gjb + g * 4 - NN / 2);
                float s1, c1;
                sincosf(th1, &s1, &c1);
#pragma unroll
                for (int k = 0; k < 4; ++k) {
                    float cc = c1 * c2v, ss = s1 * s2v, sc = s1 * c2v, cs = c1 * s2v;
                    float cpp = cc - ss, cpm = cc + ss, spp = sc + cs, spm = sc - cs;
                    float re = fmaf(A35, c1, ar4); re = fmaf(A17, c2v, re);
                    re = fmaf(A08, cpp, re);       re = fmaf(A26, cpm, re);
                    float im = B53 * s1;           im = fmaf(B71, s2v, im);
                    im = fmaf(B80, spp, im);       im = fmaf(B26, spm, im);
                    float zre = fmaf(-tau, re, 1.0f);
                    float zim = tau * im;
                    float m2 = fmaf(zre, zre, zim * zim);
                    lv[g * 4 + k] = m2 * m2 * sqrtf(m2);   // |z|^5
                    float tt = s1 * SDR;
                    float ns = fmaf(s1, CDR, c1 * SDR);
                    c1 = fmaf(c1, CDR, -tt);
                    s1 = ns;
                }
            }
        }
        float acc[16];
#pragma unroll
        for (int k = 0; k < 16; ++k) acc[k] = 0.f;
        for (int hh = 0; hh < HID; ++hh) {
            float w1a = W1[2 * hh], w1b = W1[2 * hh + 1], bb = b1[hh], wo = W2[hh];
#pragma unroll
            for (int k = 0; k < 16; ++k) {
                float v = fmaf(w1a, lv[k], fmaf(w1b, rv[k], bb));
                float m = v * fmaf(GELU_K2, v * v, GELU_K1);
                float e = __builtin_amdgcn_exp2f(m);
                float g = v * __builtin_amdgcn_rcpf(1.0f + e);
                acc[k] = fmaf(wo, g, acc[k]);
            }
        }
        float4* xo4 = (float4*)(xout + (size_t)b * NN * NN + (size_t)gi * NN + gjb);
#pragma unroll
        for (int q = 0; q < 4; ++q) {
            float4 ov;
            ov.x = w1[q * 4 + 1] + acc[q * 4] + b2v;
            ov.y = w1[q * 4 + 2] + acc[q * 4 + 1] + b2v;
            ov.z = w1[q * 4 + 3] + acc[q * 4 + 2] + b2v;
            ov.w = w1[q * 4 + 4] + acc[q * 4 + 3] + b2v;
            xo4[q] = ov;
        }
    } else {
        // ---- register-light residual path: no x store, fused norm ----
        // r_pre = f - A(w), row-by-row so only 18 w values are live at once
        float rv[16];
        {
            float w[18];
#pragma unroll
            for (int k = 0; k < 18; ++k) w[k] = pw[k];
#pragma unroll
            for (int k = 0; k < 16; ++k) {
                float ax = ar0 * w[k];
                ax = fmaf(ar1, w[k + 1], ax);
                rv[k] = fmaf(ar2, w[k + 2], ax);
            }
#pragma unroll
            for (int k = 0; k < 18; ++k) w[k] = pw[TWP + k];
#pragma unroll
            for (int k = 0; k < 16; ++k) {
                float ax = fmaf(ar3, w[k], rv[k]);
                ax = fmaf(ar4, w[k + 1], ax);
                rv[k] = fmaf(ar5, w[k + 2], ax);
            }
#pragma unroll
            for (int k = 0; k < 18; ++k) w[k] = pw[2 * TWP + k];
#pragma unroll
            for (int k = 0; k < 16; ++k) {
                float ax = fmaf(ar6, w[k], rv[k]);
                ax = fmaf(ar7, w[k + 1], ax);
                rv[k] = fmaf(ar8, w[k + 2], ax);
            }
        }
        float f2 = 0.f;
        {
            const float4* f4 = (const float4*)(fg + (size_t)gi * NN + gjb);
#pragma unroll
            for (int q = 0; q < 4; ++q) {
                float4 fq = f4[q];
                rv[q * 4]     = fq.x - rv[q * 4];
                rv[q * 4 + 1] = fq.y - rv[q * 4 + 1];
                rv[q * 4 + 2] = fq.z - rv[q * 4 + 2];
                rv[q * 4 + 3] = fq.w - rv[q * 4 + 3];
                f2 = fmaf(fq.x, fq.x, f2);
                f2 = fmaf(fq.y, fq.y, f2);
                f2 = fmaf(fq.z, fq.z, f2);
                f2 = fmaf(fq.w, fq.w, f2);
            }
        }

        // ---- ring-cell H: the 66x66 frame around the 64x64 output region.
        // Ring cells are >= 11 cells from the tile rim -> their sweep values
        // (and therefore H) are bit-identical to the neighbor block's own
        // computation. 260 cells: every thread takes one, threads 0..3 take 2.
        // LFA computed on the fly (same group-of-4 rotation scheme).
        float Hr0 = 0.f, Hr1 = 0.f;
        int hoff0 = 0, hoff1 = 0;
        auto ringH = [&](int rc, float& Hv, int& hoff) {
            int R, C;
            if (rc < 66)       { R = 15; C = 15 + rc; }
            else if (rc < 132) { R = 80; C = rc - 51; }
            else if (rc < 196) { R = rc - 116; C = 15; }
            else               { R = rc - 180; C = 80; }
            hoff = R * TWP + C;
            int rgi = goi + R, rgj = goj + C;
            Hv = 0.f;
            if (rgi >= 0 && rgi < NN && rgj >= 0 && rgj < NN) {
                const float* pr = sx + (R - 1) * TWP + (C - 1);
                float u0 = pr[0], u1 = pr[1], u2 = pr[2];
                float m0 = pr[TWP], m1 = pr[TWP + 1], m2 = pr[TWP + 2];
                float d0 = pr[2 * TWP], d1 = pr[2 * TWP + 1], d2 = pr[2 * TWP + 2];
                float ax = ar0 * u0;
                ax = fmaf(ar1, u1, ax); ax = fmaf(ar2, u2, ax);
                ax = fmaf(ar3, m0, ax); ax = fmaf(ar4, m1, ax);
                ax = fmaf(ar5, m2, ax); ax = fmaf(ar6, d0, ax);
                ax = fmaf(ar7, d1, ax); ax = fmaf(ar8, d2, ax);
                float rp = fg[(size_t)rgi * NN + rgj] - ax;
                // LFA on the fly (bit-identical: group base = rgj & ~3)
                float lf;
                {
                    float th2 = TPH * (float)(rgi - NN / 2);
                    float s2v, c2v;
                    sincosf(th2, &s2v, &c2v);
                    float th1 = TPH * (float)((rgj & ~3) - NN / 2);
                    float s1, c1;
                    sincosf(th1, &s1, &c1);
                    int rmd = rgj & 3;
                    for (int k = 0; k < rmd; ++k) {
                        float tt = s1 * SDR;
                        float ns = fmaf(s1, CDR, c1 * SDR);
                        c1 = fmaf(c1, CDR, -tt);
                        s1 = ns;
                    }
                    float cc = c1 * c2v, ss = s1 * s2v, sc = s1 * c2v, cs = c1 * s2v;
                    float cpp = cc - ss, cpm = cc + ss, spp = sc + cs, spm = sc - cs;
                    float re = fmaf(A35, c1, ar4); re = fmaf(A17, c2v, re);
                    re = fmaf(A08, cpp, re);       re = fmaf(A26, cpm, re);
                    float im = B53 * s1;           im = fmaf(B71, s2v, im);
                    im = fmaf(B80, spp, im);       im = fmaf(B26, spm, im);
                    float zre = fmaf(-tau, re, 1.0f);
                    float zim = tau * im;
                    float m2 = fmaf(zre, zre, zim * zim);
                    lf = m2 * m2 * sqrtf(m2);
                }
                float av = 0.f;
                for (int hh = 0; hh < HID; ++hh) {
                    float w1a = W1[2 * hh], w1b = W1[2 * hh + 1], bbv = b1[hh], wo = W2[hh];
                    float v = fmaf(w1a, lf, fmaf(w1b, rp, bbv));
                    float m = v * fmaf(GELU_K2, v * v, GELU_K1);
                    float e = __builtin_amdgcn_exp2f(m);
                    float gg = v * __builtin_amdgcn_rcpf(1.0f + e);
                    av = fmaf(wo, gg, av);
                }
                Hv = av + b2v;
            }
        };
        ringH(t, Hr0, hoff0);
        if (t < 4) ringH(t + 256, Hr1, hoff1);

        // ---- own-cell MLP: lv computed in-register just-in-time ----
        float acc[16];
#pragma unroll
        for (int k = 0; k < 16; ++k) acc[k] = 0.f;
        {
            float lv[16];
            {
                float th2 = TPH * (float)(gi - NN / 2);
                float s2v, c2v;
                sincosf(th2, &s2v, &c2v);
                for (int g = 0; g < 4; ++g) {
                    float th1 = TPH * (float)(gjb + g * 4 - NN / 2);
                    float s1, c1;
                    sincosf(th1, &s1, &c1);
#pragma unroll
                    for (int k = 0; k < 4; ++k) {
                        float cc = c1 * c2v, ss = s1 * s2v, sc = s1 * c2v, cs = c1 * s2v;
                        float cpp = cc - ss, cpm = cc + ss, spp = sc + cs, spm = sc - cs;
                        float re = fmaf(A35, c1, ar4); re = fmaf(A17, c2v, re);
                        re = fmaf(A08, cpp, re);       re = fmaf(A26, cpm, re);
                        float im = B53 * s1;           im = fmaf(B71, s2v, im);
                        im = fmaf(B80, spp, im);       im = fmaf(B26, spm, im);
                        float zre = fmaf(-tau, re, 1.0f);
                        float zim = tau * im;
                        float m2 = fmaf(zre, zre, zim * zim);
                        lv[g * 4 + k] = m2 * m2 * sqrtf(m2);
                        float tt = s1 * SDR;
                        float ns = fmaf(s1, CDR, c1 * SDR);
                        c1 = fmaf(c1, CDR, -tt);
                        s1 = ns;
                    }
                }
            }
            for (int hh = 0; hh < HID; ++hh) {
                float w1a = W1[2 * hh], w1b = W1[2 * hh + 1], bb = b1[hh], wo = W2[hh];
#pragma unroll
                for (int k = 0; k < 16; ++k) {
                    float v = fmaf(w1a, lv[k], fmaf(w1b, rv[k], bb));
                    float m = v * fmaf(GELU_K2, v * v, GELU_K1);
                    float e = __builtin_amdgcn_exp2f(m);
                    float g = v * __builtin_amdgcn_rcpf(1.0f + e);
                    acc[k] = fmaf(wo, g, acc[k]);
                }
            }
        }

        __syncthreads();   // all LDS w-reads (own + ring) complete
        // publish H on [15,81)^2 in place over the sweep tile
        float* ph = sx + Rl * TWP + Cl0;
#pragma unroll
        for (int k = 0; k < 16; ++k) ph[k] = acc[k] + b2v;
        sx[hoff0] = Hr0;
        if (t < 4) sx[hoff1] = Hr1;
        __syncthreads();   // H tile visible

        // r_final = r_pre - A(H), row-by-row to keep live range small
        float rr = 0.f;
        {
            float hr[18];
#pragma unroll
            for (int k = 0; k < 18; ++k) hr[k] = pw[k];
#pragma unroll
            for (int k = 0; k < 16; ++k) {
                float ax = ar0 * hr[k];
                ax = fmaf(ar1, hr[k + 1], ax);
                ax = fmaf(ar2, hr[k + 2], ax);
                rv[k] -= ax;
            }
#pragma unroll
            for (int k = 0; k < 18; ++k) hr[k] = pw[TWP + k];
#pragma unroll
            for (int k = 0; k < 16; ++k) {
                float ax = ar3 * hr[k];
                ax = fmaf(ar4, hr[k + 1], ax);
                ax = fmaf(ar5, hr[k + 2], ax);
                rv[k] -= ax;
            }
#pragma unroll
            for (int k = 0; k < 18; ++k) hr[k] = pw[2 * TWP + k];
#pragma unroll
            for (int k = 0; k < 16; ++k) {
                float ax = ar6 * hr[k];
                ax = fmaf(ar7, hr[k + 1], ax);
                ax = fmaf(ar8, hr[k + 2], ax);
                float r = rv[k] - ax;
                rr = fmaf(r, r, rr);
            }
        }
        // block reduction -> one atomicAdd pair; LAST block finalizes
#pragma unroll
        for (int off = 32; off > 0; off >>= 1) {
            rr += __shfl_down(rr, off, 64);
            f2 += __shfl_down(f2, off, 64);
        }
        if ((t & 63) == 0) { sxraw[t >> 6] = rr; sxraw[4 + (t >> 6)] = f2; }
        __syncthreads();
        if (t == 0) {
            atomicAdd(&accp[0], sxraw[0] + sxraw[1] + sxraw[2] + sxraw[3]);
            atomicAdd(&accp[1], sxraw[4] + sxraw[5] + sxraw[6] + sxraw[7]);
            __threadfence();
            unsigned int done = atomicAdd((unsigned int*)accp + 2, 1u);
            if (done == (NN / OT) * (NN / OT) * BB - 1) {
                __threadfence();
                float rrt = atomicAdd(&accp[0], 0.f);   // coherent (L2) read
                float fft = atomicAdd(&accp[1], 0.f);
                outp[0] = sqrtf(rrt / fft);
            }
        }
    }
}

// ---------------------------------------------------------------------------
extern "C" void kernel_launch(void* const* d_in, const int* in_sizes, int n_in,
                              void* d_out, int out_size, void* d_ws, size_t ws_size,
                              hipStream_t stream) {
    const float* f  = (const float*)d_in[0];
    const float* kA = (const float*)d_in[1];
    float*       u  = (float*)d_in[2];   // scratch (fully overwritten by cycle 2)
    const float* W1 = (const float*)d_in[3];
    const float* b1 = (const float*)d_in[4];
    const float* W2 = (const float*)d_in[5];
    const float* b2 = (const float*)d_in[6];
    float* out = (float*)d_out;

    char* ws = (char*)d_ws;
    float* acc = (float*)ws;              // 12 B: sum(r^2), sum(f^2), counter
    float* xB  = (float*)(ws + 256);      // 16 MiB

    dim3 jblk(32, 8);
    dim3 jgrd(NN / OT, NN / OT, BB);

    // cycle 1 (x = 0, collapsed sweep 0; zeroes acc), cycle 2,
    // cycle 3 (fused residual norm + last-block finalize, no x store)
    fused_cycle<true,  false><<<jgrd, jblk, 0, stream>>>(u, xB, f, kA, W1, b1, W2, b2, acc, out);
    fused_cycle<false, false><<<jgrd, jblk, 0, stream>>>(xB, u, f, kA, W1, b1, W2, b2, acc, out);
    fused_cycle<false, true ><<<jgrd, jblk, 0, stream>>>(u, xB, f, kA, W1, b1, W2, b2, acc, out);
}

// Round 4
// 393.591 us; speedup vs baseline: 1.2983x; 1.2983x over previous
//
#include <hip/hip_runtime.h>
#include <math.h>

#define BB 16
#define NN 512
#define HID 32

#define HALO 16
#define TW 96        // logical tile width (64 + 2*HALO)
#define TWP 97       // LDS pitch: 97 % 32 == 1 -> conflict-free Phase D
#define OT 64

// fast tanh-approx GELU: gelu(v) = v / (1 + exp2(K1*v + K2*v^3))
#define GELU_K1 (-2.302208201f)
#define GELU_K2 (-0.102944244f)

// LFA angle step 2*pi/513 and its cos/sin
#define TPH 0.012247925f
#define CDR 0.99992499f
#define SDR 0.012247618f

// ---------------------------------------------------------------------------
// LFA map, vectorized: 4 consecutive columns per thread via one sincos pair +
// 2-fma angle rotation; float4 store. (R10-proven, ~12 us.)
// MEASURED (rounds 2 & 3): folding this into fused_cycle — as a FIRST
// pre-block OR as in-register Phase-D compute — tips that instantiation to
// 132 VGPR (113.7 -> 135..196 us). Keep it a separate kernel.
// ---------------------------------------------------------------------------
__global__ __launch_bounds__(256) void lfa_kernel(const float* __restrict__ kernelA,
                                                  float* __restrict__ lfa) {
    const int t = threadIdx.x;
    const int strip = t & 127;           // 128 strips of 4 cols
    const int i = blockIdx.y * 2 + (t >> 7);
    const int b = blockIdx.z;
    const int j0 = strip * 4;
    const float* a = kernelA + b * 9;
    float a0 = a[0], a1 = a[1], a2 = a[2], a3 = a[3], a4 = a[4];
    float a5 = a[5], a6 = a[6], a7 = a[7], a8 = a[8];
    const float A35 = a3 + a5, A17 = a1 + a7, A08 = a0 + a8, A26 = a2 + a6;
    const float B53 = a5 - a3, B71 = a7 - a1, B80 = a8 - a0, B26 = a2 - a6;
    const float tau = 0.5f / a4;

    float th2 = TPH * (float)(i - NN / 2);
    float th1 = TPH * (float)(j0 - NN / 2);
    float s1, c1, s2, c2;
    sincosf(th1, &s1, &c1);
    sincosf(th2, &s2, &c2);

    float out[4];
#pragma unroll
    for (int k = 0; k < 4; ++k) {
        float cc = c1 * c2, ss = s1 * s2, sc = s1 * c2, cs = c1 * s2;
        float cpp = cc - ss, cpm = cc + ss, spp = sc + cs, spm = sc - cs;
        float re = fmaf(A35, c1, a4); re = fmaf(A17, c2, re);
        re = fmaf(A08, cpp, re);      re = fmaf(A26, cpm, re);
        float im = B53 * s1;          im = fmaf(B71, s2, im);
        im = fmaf(B80, spp, im);      im = fmaf(B26, spm, im);
        float zre = fmaf(-tau, re, 1.0f);
        float zim = tau * im;
        float m2 = fmaf(zre, zre, zim * zim);
        out[k] = m2 * m2 * sqrtf(m2);   // |z|^5
        // rotate theta1 by one column step
        float tt = s1 * SDR;
        float ns = fmaf(s1, CDR, c1 * SDR);
        c1 = fmaf(c1, CDR, -tt);
        s1 = ns;
    }
    float4 ov = {out[0], out[1], out[2], out[3]};
    *(float4*)(lfa + (size_t)b * NN * NN + (size_t)i * NN + j0) = ov;
}

// ---------------------------------------------------------------------------
// One full cycle: 10 Jacobi sweeps (register-resident 12x3 blocks, LDS halo
// exchange only) + fused pointwise-MLP correction (thread-remapped, 1x work)
// Guard-ring LDS tile: logical (row,col) in [-1,96]^2, physically in-bounds;
// guards zeroed once -> NO clamps, and every LDS access is one base pointer
// + compile-time immediate. Proven config: 128 VGPR, 4 waves/SIMD.
// DO NOT add live state near Phase C/D: every attempt tipped to 132 VGPR
// (+20..80 us/cycle). DO NOT use __launch_bounds__(256,4): round-1 measured
// the backend targets the 64-VGPR bucket and spills (FETCH 39->391 MB).
// DO NOT inline LFA generation anywhere in this kernel (rounds 2 & 3).
// FIRST: x0 = 0, sweep 0 collapses to cur = mask*(tau*f); tile fill skipped;
//        zeroes the accumulator/counter slots (replaces hipMemsetAsync).
// RES:   cycle-3 variant (round-2 verified). No x store. r_final =
//        r_pre - A(H) via an H-ring exchange through the LDS tile (ring
//        cells are bit-exact recomputations: contamination depth after 10
//        sweeps is 10 < 15). Block-reduces sum(r^2), sum(f^2) into accp;
//        the LAST block computes the final norm (device-scope counter) ->
//        no finalize dispatch (round-3 verified correct).
// ---------------------------------------------------------------------------
template <bool FIRST, bool RES>
__global__ __launch_bounds__(256) void fused_cycle(
        const float* __restrict__ xin, float* __restrict__ xout,
        const float* __restrict__ f, const float* __restrict__ kernelA,
        const float* __restrict__ lfa,
        const float* __restrict__ W1, const float* __restrict__ b1,
        const float* __restrict__ W2, const float* __restrict__ b2,
        float* __restrict__ accp, float* __restrict__ outp) {
    __shared__ float sxraw[98 * TWP + 2];
    float* sx = sxraw + TWP + 1;   // logical origin (0,0); row r col c -> sx[r*TWP+c]
    const int tx = threadIdx.x;   // 0..31
    const int ty = threadIdx.y;   // 0..7
    const int t  = ty * 32 + tx;
    const int b  = blockIdx.z;
    const int gy0 = blockIdx.y * OT;
    const int gx0 = blockIdx.x * OT;
    const int goi = gy0 - HALO;
    const int goj = gx0 - HALO;
    const float* fg = f + (size_t)b * NN * NN;
    const float* ag = kernelA + b * 9;   // uniform -> s_load
    const float ar0 = ag[0], ar1 = ag[1], ar2 = ag[2], ar3 = ag[3], ar4 = ag[4];
    const float ar5 = ag[5], ar6 = ag[6], ar7 = ag[7], ar8 = ag[8];
    const float tau = 0.5f / ar4;
    // tau-scaled stencil for the sweeps
    const float s0 = tau * ar0, q1 = tau * ar1, q2 = tau * ar2, q3 = tau * ar3;
    const float q4 = tau * ar4, q5 = tau * ar5, q6 = tau * ar6, q7 = tau * ar7;
    const float q8 = tau * ar8;

    if (FIRST) {
        // zero norm accumulators + done-counter (stream order puts this
        // before cycle-3's atomics)
        if (t == 0 && (blockIdx.x | blockIdx.y | blockIdx.z) == 0) {
            accp[0] = 0.f;
            accp[1] = 0.f;
            ((unsigned int*)accp)[2] = 0u;
        }
    }

    // ---- zero the guard ring (top band, shared L/R col guards, bottom band)
    if (t < 98) sxraw[t] = 0.f;                 // logical row -1, col -1..96
    if (t < 96) sxraw[97 + 97 * t] = 0.f;       // col -1 of row t (== col 96 of row t-1)
    if (t < 98) sxraw[9409 + t] = 0.f;          // logical row 96, col -1..96

    // ---- Phase A: tile -> LDS (interior 96x96); skipped for FIRST ----
    if (!FIRST) {
        const float* xg = xin + (size_t)b * NN * NN;
#pragma unroll
        for (int k = 0; k < (TW * TW) / 256; ++k) {
            int idx = t + k * 256;
            int row = idx / TW, col = idx - row * TW;
            int gi = goi + row, gj = goj + col;
            float v = 0.f;
            if (gi >= 0 && gi < NN && gj >= 0 && gj < NN) v = xg[gi * NN + gj];
            sx[row * TWP + col] = v;
        }
    }

    const int R0 = ty * 12, C0 = tx * 3;

    // single base pointers: all LDS traffic below is base + compile-time imm
    const float* pb  = sx + (R0 - 1) * TWP + (C0 - 1);  // extended-block origin
    float*       pwv = sx + R0 * TWP + C0;              // owned-cell origin

    // masks: cell updates only if tile-interior AND inside global domain
    float vR[12], vC[3];
#pragma unroll
    for (int r = 0; r < 12; ++r) {
        int R = R0 + r, gi = goi + R;
        vR[r] = (R >= 1 && R < TW - 1 && gi >= 0 && gi < NN) ? 1.f : 0.f;
    }
#pragma unroll
    for (int c = 0; c < 3; ++c) {
        int C = C0 + c, gj = goj + C;
        vC[c] = (C >= 1 && C < TW - 1 && gj >= 0 && gj < NN) ? 1.f : 0.f;
    }

    // tau-scaled f for owned cells (0 outside domain)
    float frt[12][3];
#pragma unroll
    for (int r = 0; r < 12; ++r) {
        int gi = goi + R0 + r;
#pragma unroll
        for (int c = 0; c < 3; ++c) {
            int gj = goj + C0 + c;
            frt[r][c] = (gi >= 0 && gi < NN && gj >= 0 && gj < NN)
                            ? tau * fg[gi * NN + gj] : 0.f;
        }
    }

    __syncthreads();   // tile + guards visible

    // ---- Phase B: own cells -> registers ----
    float cur[12][3];
    if (FIRST) {
        // collapsed sweep 0: x1 = mask * (tau*f); publish borders
#pragma unroll
        for (int r = 0; r < 12; ++r) {
#pragma unroll
            for (int c = 0; c < 3; ++c)
                cur[r][c] = (vR[r] * vC[c]) * frt[r][c];
        }
        pwv[0] = cur[0][0]; pwv[1] = cur[0][1]; pwv[2] = cur[0][2];
        pwv[11 * TWP] = cur[11][0]; pwv[11 * TWP + 1] = cur[11][1];
        pwv[11 * TWP + 2] = cur[11][2];
#pragma unroll
        for (int r = 1; r < 11; ++r) {
            pwv[r * TWP] = cur[r][0];
            pwv[r * TWP + 2] = cur[r][2];
        }
        __syncthreads();   // sweep-0 borders visible
    } else {
#pragma unroll
        for (int r = 0; r < 12; ++r) {
            cur[r][0] = pwv[r * TWP];
            cur[r][1] = pwv[r * TWP + 1];
            cur[r][2] = pwv[r * TWP + 2];
        }
    }

    // ---- Phase C: sweeps (FIRST starts at s=1: sweep 0 was collapsed) ----
    for (int s = FIRST ? 1 : 0; s < 10; ++s) {
        // halo reads (34), all immediate offsets off pb
        float top0 = pb[0], top1 = pb[1], top2 = pb[2], top3 = pb[3], top4 = pb[4];
        float bot0 = pb[13 * TWP],     bot1 = pb[13 * TWP + 1],
              bot2 = pb[13 * TWP + 2], bot3 = pb[13 * TWP + 3],
              bot4 = pb[13 * TWP + 4];
        float pm0 = top1, pm1v = top2, pm2 = top3;
        float Lm1 = top0, Rm1 = top4;
        float Lc = pb[TWP], Rc = pb[TWP + 4];
#pragma unroll
        for (int r = 0; r < 12; ++r) {
            float n0, n1, n2, Lp, Rp;
            if (r < 11) {
                n0 = cur[r + 1][0]; n1 = cur[r + 1][1]; n2 = cur[r + 1][2];
                Lp = pb[(r + 2) * TWP];
                Rp = pb[(r + 2) * TWP + 4];
            } else {
                n0 = bot1; n1 = bot2; n2 = bot3; Lp = bot0; Rp = bot4;
            }
            float o0 = cur[r][0], o1 = cur[r][1], o2 = cur[r][2];
            // c = 0
            {
                float ax = s0 * Lm1;
                ax = fmaf(q1, pm0, ax); ax = fmaf(q2, pm1v, ax);
                ax = fmaf(q3, Lc, ax);  ax = fmaf(q4, o0, ax);
                ax = fmaf(q5, o1, ax);  ax = fmaf(q6, Lp, ax);
                ax = fmaf(q7, n0, ax);  ax = fmaf(q8, n1, ax);
                cur[r][0] = fmaf(vR[r] * vC[0], frt[r][0] - ax, o0);
            }
            // c = 1
            {
                float ax = s0 * pm0;
                ax = fmaf(q1, pm1v, ax); ax = fmaf(q2, pm2, ax);
                ax = fmaf(q3, o0, ax);   ax = fmaf(q4, o1, ax);
                ax = fmaf(q5, o2, ax);   ax = fmaf(q6, n0, ax);
                ax = fmaf(q7, n1, ax);   ax = fmaf(q8, n2, ax);
                cur[r][1] = fmaf(vR[r] * vC[1], frt[r][1] - ax, o1);
            }
            // c = 2
            {
                float ax = s0 * pm1v;
                ax = fmaf(q1, pm2, ax); ax = fmaf(q2, Rm1, ax);
                ax = fmaf(q3, o1, ax);  ax = fmaf(q4, o2, ax);
                ax = fmaf(q5, Rc, ax);  ax = fmaf(q6, n1, ax);
                ax = fmaf(q8, Rp, fmaf(q7, n2, ax));
                cur[r][2] = fmaf(vR[r] * vC[2], frt[r][2] - ax, o2);
            }
            pm0 = o0; pm1v = o1; pm2 = o2;
            Lm1 = Lc; Rm1 = Rc; Lc = Lp; Rc = Rp;
        }
        __syncthreads();   // all halo reads done
        if (s < 9) {
            // write border cells (26)
            pwv[0] = cur[0][0]; pwv[1] = cur[0][1]; pwv[2] = cur[0][2];
            pwv[11 * TWP] = cur[11][0]; pwv[11 * TWP + 1] = cur[11][1];
            pwv[11 * TWP + 2] = cur[11][2];
#pragma unroll
            for (int r = 1; r < 11; ++r) {
                pwv[r * TWP] = cur[r][0];
                pwv[r * TWP + 2] = cur[r][2];
            }
        } else {
            // final sweep: publish ALL cells for the correction phase
#pragma unroll
            for (int r = 0; r < 12; ++r) {
                pwv[r * TWP] = cur[r][0];
                pwv[r * TWP + 1] = cur[r][1];
                pwv[r * TWP + 2] = cur[r][2];
            }
        }
        __syncthreads();   // writes visible
    }

    // ---- Phase D: remapped correction, exactly 1x MLP work ----
    // thread t -> output row orow = t/4 (0..63), column segment oseg = t%4
    // Pitch 97: bank = orow + 16*oseg + k + const (mod 32) -> 2 lanes/bank (free).
    const int orow = t >> 2;
    const int oseg = t & 3;
    const int Rl = HALO + orow;           // 16..79
    const int Cl0 = HALO + oseg * 16;     // 16,32,48,64
    const float* pw = sx + (Rl - 1) * TWP + (Cl0 - 1);   // single base + imm
    const int gi = gy0 + orow;
    const int gjb = gx0 + oseg * 16;
    const float b2v = b2[0];

    if (!RES) {
        // ---- round-0-proven path (128 VGPR): bulk w loads, output store ----
        float w0[18], w1[18], w2[18];
#pragma unroll
        for (int k = 0; k < 18; ++k) {
            w0[k] = pw[k];
            w1[k] = pw[TWP + k];
            w2[k] = pw[2 * TWP + k];
        }
        const float4* f4 = (const float4*)(fg + (size_t)gi * NN + gjb);
        const float4* l4 = (const float4*)(lfa + (size_t)b * NN * NN + (size_t)gi * NN + gjb);
        float fv[16], lv[16];
#pragma unroll
        for (int q = 0; q < 4; ++q) {
            float4 fq = f4[q], lq = l4[q];
            fv[q * 4] = fq.x; fv[q * 4 + 1] = fq.y; fv[q * 4 + 2] = fq.z; fv[q * 4 + 3] = fq.w;
            lv[q * 4] = lq.x; lv[q * 4 + 1] = lq.y; lv[q * 4 + 2] = lq.z; lv[q * 4 + 3] = lq.w;
        }
        float rv[16];
#pragma unroll
        for (int k = 0; k < 16; ++k) {
            float ax = ar0 * w0[k];
            ax = fmaf(ar1, w0[k + 1], ax); ax = fmaf(ar2, w0[k + 2], ax);
            ax = fmaf(ar3, w1[k], ax);     ax = fmaf(ar4, w1[k + 1], ax);
            ax = fmaf(ar5, w1[k + 2], ax); ax = fmaf(ar6, w2[k], ax);
            ax = fmaf(ar7, w2[k + 1], ax); ax = fmaf(ar8, w2[k + 2], ax);
            rv[k] = fv[k] - ax;
        }
        float acc[16];
#pragma unroll
        for (int k = 0; k < 16; ++k) acc[k] = 0.f;
        for (int hh = 0; hh < HID; ++hh) {
            float w1a = W1[2 * hh], w1b = W1[2 * hh + 1], bb = b1[hh], wo = W2[hh];
#pragma unroll
            for (int k = 0; k < 16; ++k) {
                float v = fmaf(w1a, lv[k], fmaf(w1b, rv[k], bb));
                float m = v * fmaf(GELU_K2, v * v, GELU_K1);
                float e = __builtin_amdgcn_exp2f(m);
                float g = v * __builtin_amdgcn_rcpf(1.0f + e);
                acc[k] = fmaf(wo, g, acc[k]);
            }
        }
        float4* xo4 = (float4*)(xout + (size_t)b * NN * NN + (size_t)gi * NN + gjb);
#pragma unroll
        for (int q = 0; q < 4; ++q) {
            float4 ov;
            ov.x = w1[q * 4 + 1] + acc[q * 4] + b2v;
            ov.y = w1[q * 4 + 2] + acc[q * 4 + 1] + b2v;
            ov.z = w1[q * 4 + 3] + acc[q * 4 + 2] + b2v;
            ov.w = w1[q * 4 + 4] + acc[q * 4 + 3] + b2v;
            xo4[q] = ov;
        }
    } else {
        // ---- round-2-verified register-light residual path ----
        // r_pre = f - A(w), row-by-row so only 18 w values are live at once
        float rv[16];
        {
            float w[18];
#pragma unroll
            for (int k = 0; k < 18; ++k) w[k] = pw[k];
#pragma unroll
            for (int k = 0; k < 16; ++k) {
                float ax = ar0 * w[k];
                ax = fmaf(ar1, w[k + 1], ax);
                rv[k] = fmaf(ar2, w[k + 2], ax);
            }
#pragma unroll
            for (int k = 0; k < 18; ++k) w[k] = pw[TWP + k];
#pragma unroll
            for (int k = 0; k < 16; ++k) {
                float ax = fmaf(ar3, w[k], rv[k]);
                ax = fmaf(ar4, w[k + 1], ax);
                rv[k] = fmaf(ar5, w[k + 2], ax);
            }
#pragma unroll
            for (int k = 0; k < 18; ++k) w[k] = pw[2 * TWP + k];
#pragma unroll
            for (int k = 0; k < 16; ++k) {
                float ax = fmaf(ar6, w[k], rv[k]);
                ax = fmaf(ar7, w[k + 1], ax);
                rv[k] = fmaf(ar8, w[k + 2], ax);
            }
        }
        float f2 = 0.f;
        {
            const float4* f4 = (const float4*)(fg + (size_t)gi * NN + gjb);
#pragma unroll
            for (int q = 0; q < 4; ++q) {
                float4 fq = f4[q];
                rv[q * 4]     = fq.x - rv[q * 4];
                rv[q * 4 + 1] = fq.y - rv[q * 4 + 1];
                rv[q * 4 + 2] = fq.z - rv[q * 4 + 2];
                rv[q * 4 + 3] = fq.w - rv[q * 4 + 3];
                f2 = fmaf(fq.x, fq.x, f2);
                f2 = fmaf(fq.y, fq.y, f2);
                f2 = fmaf(fq.z, fq.z, f2);
                f2 = fmaf(fq.w, fq.w, f2);
            }
        }

        // ---- ring-cell H: the 66x66 frame around the 64x64 output region.
        // Ring cells are >= 11 cells from the tile rim -> their sweep values
        // (and therefore H) are bit-identical to the neighbor block's own
        // computation. 260 cells: every thread takes one, threads 0..3 take 2.
        // Runs while only rv[16] + f2 are live. LFA read from the buffer.
        float Hr0 = 0.f, Hr1 = 0.f;
        int hoff0 = 0, hoff1 = 0;
        auto ringH = [&](int rc, float& Hv, int& hoff) {
            int R, C;
            if (rc < 66)       { R = 15; C = 15 + rc; }
            else if (rc < 132) { R = 80; C = rc - 51; }
            else if (rc < 196) { R = rc - 116; C = 15; }
            else               { R = rc - 180; C = 80; }
            hoff = R * TWP + C;
            int rgi = goi + R, rgj = goj + C;
            Hv = 0.f;
            if (rgi >= 0 && rgi < NN && rgj >= 0 && rgj < NN) {
                const float* pr = sx + (R - 1) * TWP + (C - 1);
                float u0 = pr[0], u1 = pr[1], u2 = pr[2];
                float m0 = pr[TWP], m1 = pr[TWP + 1], m2 = pr[TWP + 2];
                float d0 = pr[2 * TWP], d1 = pr[2 * TWP + 1], d2 = pr[2 * TWP + 2];
                float ax = ar0 * u0;
                ax = fmaf(ar1, u1, ax); ax = fmaf(ar2, u2, ax);
                ax = fmaf(ar3, m0, ax); ax = fmaf(ar4, m1, ax);
                ax = fmaf(ar5, m2, ax); ax = fmaf(ar6, d0, ax);
                ax = fmaf(ar7, d1, ax); ax = fmaf(ar8, d2, ax);
                float rp = fg[(size_t)rgi * NN + rgj] - ax;
                float lf = lfa[(size_t)b * NN * NN + (size_t)rgi * NN + rgj];
                float av = 0.f;
                for (int hh = 0; hh < HID; ++hh) {
                    float w1a = W1[2 * hh], w1b = W1[2 * hh + 1], bbv = b1[hh], wo = W2[hh];
                    float v = fmaf(w1a, lf, fmaf(w1b, rp, bbv));
                    float m = v * fmaf(GELU_K2, v * v, GELU_K1);
                    float e = __builtin_amdgcn_exp2f(m);
                    float gg = v * __builtin_amdgcn_rcpf(1.0f + e);
                    av = fmaf(wo, gg, av);
                }
                Hv = av + b2v;
            }
        };
        ringH(t, Hr0, hoff0);
        if (t < 4) ringH(t + 256, Hr1, hoff1);

        // ---- own-cell MLP: lv loaded just-in-time ----
        float acc[16];
#pragma unroll
        for (int k = 0; k < 16; ++k) acc[k] = 0.f;
        {
            float lv[16];
            const float4* l4 = (const float4*)(lfa + (size_t)b * NN * NN + (size_t)gi * NN + gjb);
#pragma unroll
            for (int q = 0; q < 4; ++q) {
                float4 lq = l4[q];
                lv[q * 4] = lq.x; lv[q * 4 + 1] = lq.y;
                lv[q * 4 + 2] = lq.z; lv[q * 4 + 3] = lq.w;
            }
            for (int hh = 0; hh < HID; ++hh) {
                float w1a = W1[2 * hh], w1b = W1[2 * hh + 1], bb = b1[hh], wo = W2[hh];
#pragma unroll
                for (int k = 0; k < 16; ++k) {
                    float v = fmaf(w1a, lv[k], fmaf(w1b, rv[k], bb));
                    float m = v * fmaf(GELU_K2, v * v, GELU_K1);
                    float e = __builtin_amdgcn_exp2f(m);
                    float g = v * __builtin_amdgcn_rcpf(1.0f + e);
                    acc[k] = fmaf(wo, g, acc[k]);
                }
            }
        }

        __syncthreads();   // all LDS w-reads (own + ring) complete
        // publish H on [15,81)^2 in place over the sweep tile
        float* ph = sx + Rl * TWP + Cl0;
#pragma unroll
        for (int k = 0; k < 16; ++k) ph[k] = acc[k] + b2v;
        sx[hoff0] = Hr0;
        if (t < 4) sx[hoff1] = Hr1;
        __syncthreads();   // H tile visible

        // r_final = r_pre - A(H), row-by-row to keep live range small
        float rr = 0.f;
        {
            float hr[18];
#pragma unroll
            for (int k = 0; k < 18; ++k) hr[k] = pw[k];
#pragma unroll
            for (int k = 0; k < 16; ++k) {
                float ax = ar0 * hr[k];
                ax = fmaf(ar1, hr[k + 1], ax);
                ax = fmaf(ar2, hr[k + 2], ax);
                rv[k] -= ax;
            }
#pragma unroll
            for (int k = 0; k < 18; ++k) hr[k] = pw[TWP + k];
#pragma unroll
            for (int k = 0; k < 16; ++k) {
                float ax = ar3 * hr[k];
                ax = fmaf(ar4, hr[k + 1], ax);
                ax = fmaf(ar5, hr[k + 2], ax);
                rv[k] -= ax;
            }
#pragma unroll
            for (int k = 0; k < 18; ++k) hr[k] = pw[2 * TWP + k];
#pragma unroll
            for (int k = 0; k < 16; ++k) {
                float ax = ar6 * hr[k];
                ax = fmaf(ar7, hr[k + 1], ax);
                ax = fmaf(ar8, hr[k + 2], ax);
                float r = rv[k] - ax;
                rr = fmaf(r, r, rr);
            }
        }
        // block reduction -> one atomicAdd pair; LAST block finalizes
#pragma unroll
        for (int off = 32; off > 0; off >>= 1) {
            rr += __shfl_down(rr, off, 64);
            f2 += __shfl_down(f2, off, 64);
        }
        if ((t & 63) == 0) { sxraw[t >> 6] = rr; sxraw[4 + (t >> 6)] = f2; }
        __syncthreads();
        if (t == 0) {
            atomicAdd(&accp[0], sxraw[0] + sxraw[1] + sxraw[2] + sxraw[3]);
            atomicAdd(&accp[1], sxraw[4] + sxraw[5] + sxraw[6] + sxraw[7]);
            __threadfence();
            unsigned int done = atomicAdd((unsigned int*)accp + 2, 1u);
            if (done == (NN / OT) * (NN / OT) * BB - 1) {
                __threadfence();
                float rrt = atomicAdd(&accp[0], 0.f);   // coherent (L2) read
                float fft = atomicAdd(&accp[1], 0.f);
                outp[0] = sqrtf(rrt / fft);
            }
        }
    }
}

// ---------------------------------------------------------------------------
extern "C" void kernel_launch(void* const* d_in, const int* in_sizes, int n_in,
                              void* d_out, int out_size, void* d_ws, size_t ws_size,
                              hipStream_t stream) {
    const float* f  = (const float*)d_in[0];
    const float* kA = (const float*)d_in[1];
    float*       u  = (float*)d_in[2];   // scratch (fully overwritten by cycle 2)
    const float* W1 = (const float*)d_in[3];
    const float* b1 = (const float*)d_in[4];
    const float* W2 = (const float*)d_in[5];
    const float* b2 = (const float*)d_in[6];
    float* out = (float*)d_out;

    char* ws = (char*)d_ws;
    float* acc = (float*)ws;                                     // 12 B
    float* xB  = (float*)(ws + 256);                             // 16 MiB
    float* lfa = (float*)(ws + 256 + (size_t)BB * NN * NN * 4);  // 16 MiB

    lfa_kernel<<<dim3(1, NN / 2, BB), 256, 0, stream>>>(kA, lfa);

    dim3 jblk(32, 8);
    dim3 jgrd(NN / OT, NN / OT, BB);

    // cycle 1 (x = 0, collapsed sweep 0; zeroes acc), cycle 2,
    // cycle 3 (fused residual norm + last-block finalize, no x store)
    fused_cycle<true,  false><<<jgrd, jblk, 0, stream>>>(u, xB, f, kA, lfa, W1, b1, W2, b2, acc, out);
    fused_cycle<false, false><<<jgrd, jblk, 0, stream>>>(xB, u, f, kA, lfa, W1, b1, W2, b2, acc, out);
    fused_cycle<false, true ><<<jgrd, jblk, 0, stream>>>(u, xB, f, kA, lfa, W1, b1, W2, b2, acc, out);
}

// Round 5
// 362.234 us; speedup vs baseline: 1.4107x; 1.0866x over previous
//
#include <hip/hip_runtime.h>
#include <math.h>

#define BB 16
#define NN 512
#define HID 32

#define HALO 16
#define TW 96        // logical tile width (64 + 2*HALO)
#define TWP 97       // LDS pitch: 97 % 32 == 1 -> conflict-free Phase D
#define OT 64

// fast tanh-approx GELU: gelu(v) = v / (1 + exp2(K1*v + K2*v^3))
#define GELU_K1 (-2.302208201f)
#define GELU_K2 (-0.102944244f)

// LFA angle step 2*pi/513: rotation recurrence cos/sin
#define CDR 0.99992499f
#define SDR 0.012247618f
// 1/513 (angles in revolutions for v_sin_f32/v_cos_f32: D = sin(S0*2pi))
#define REVS 0.0019493177f

// ---------------------------------------------------------------------------
// LFA map, vectorized: 4 consecutive columns per thread via one sin/cos pair
// + 2-fma angle rotation; float4 store.
// MEASURED (rounds 2 & 3): folding this into fused_cycle — as a FIRST
// pre-block OR as in-register Phase-D compute — tips that instantiation to
// 132 VGPR (113.7 -> 135..196 us). Keep it a separate kernel. FROZEN.
// Round 5: sincosf (libm, branchy) -> v_sin_f32/v_cos_f32. Angles are
// 2pi*p/513 with |p| <= 256 -> |rev| < 0.5, native HW domain, no range
// reduction needed.
// ---------------------------------------------------------------------------
__global__ __launch_bounds__(256) void lfa_kernel(const float* __restrict__ kernelA,
                                                  float* __restrict__ lfa) {
    const int t = threadIdx.x;
    const int strip = t & 127;           // 128 strips of 4 cols
    const int i = blockIdx.y * 2 + (t >> 7);
    const int b = blockIdx.z;
    const int j0 = strip * 4;
    const float* a = kernelA + b * 9;
    float a0 = a[0], a1 = a[1], a2 = a[2], a3 = a[3], a4 = a[4];
    float a5 = a[5], a6 = a[6], a7 = a[7], a8 = a[8];
    const float A35 = a3 + a5, A17 = a1 + a7, A08 = a0 + a8, A26 = a2 + a6;
    const float B53 = a5 - a3, B71 = a7 - a1, B80 = a8 - a0, B26 = a2 - a6;
    const float tau = 0.5f / a4;

    float r1 = (float)(j0 - NN / 2) * REVS;   // revolutions, |r| < 0.5
    float r2 = (float)(i - NN / 2) * REVS;
    float s1 = __builtin_amdgcn_sinf(r1);
    float c1 = __builtin_amdgcn_cosf(r1);
    float s2 = __builtin_amdgcn_sinf(r2);
    float c2 = __builtin_amdgcn_cosf(r2);

    float out[4];
#pragma unroll
    for (int k = 0; k < 4; ++k) {
        float cc = c1 * c2, ss = s1 * s2, sc = s1 * c2, cs = c1 * s2;
        float cpp = cc - ss, cpm = cc + ss, spp = sc + cs, spm = sc - cs;
        float re = fmaf(A35, c1, a4); re = fmaf(A17, c2, re);
        re = fmaf(A08, cpp, re);      re = fmaf(A26, cpm, re);
        float im = B53 * s1;          im = fmaf(B71, s2, im);
        im = fmaf(B80, spp, im);      im = fmaf(B26, spm, im);
        float zre = fmaf(-tau, re, 1.0f);
        float zim = tau * im;
        float m2 = fmaf(zre, zre, zim * zim);
        out[k] = m2 * m2 * sqrtf(m2);   // |z|^5
        // rotate theta1 by one column step
        float tt = s1 * SDR;
        float ns = fmaf(s1, CDR, c1 * SDR);
        c1 = fmaf(c1, CDR, -tt);
        s1 = ns;
    }
    float4 ov = {out[0], out[1], out[2], out[3]};
    *(float4*)(lfa + (size_t)b * NN * NN + (size_t)i * NN + j0) = ov;
}

// ---------------------------------------------------------------------------
// One full cycle: 10 Jacobi sweeps (register-resident 12x3 blocks, LDS halo
// exchange only) + fused pointwise-MLP correction (thread-remapped, 1x work)
// Guard-ring LDS tile: logical (row,col) in [-1,96]^2, physically in-bounds;
// guards zeroed once -> NO clamps, and every LDS access is one base pointer
// + compile-time immediate. Proven config: 128 VGPR, 4 waves/SIMD.
// DO NOT add live state near Phase C/D: every attempt tipped to 132 VGPR
// (+20..80 us/cycle). DO NOT use __launch_bounds__(256,4): round-1 measured
// the backend targets the 64-VGPR bucket and spills (FETCH 39->391 MB).
// DO NOT inline LFA generation anywhere in this kernel (rounds 2 & 3).
// Round 5: Phase A vectorized to float4 (goj = gx0-16 is 16B-aligned; strips
// never straddle the domain edge since goj % 4 == 0). Values die at the
// first barrier -> no regalloc risk to Phase C/D.
// FIRST: x0 = 0, sweep 0 collapses to cur = mask*(tau*f); tile fill skipped;
//        zeroes the accumulator/counter slots (replaces hipMemsetAsync).
// RES:   cycle-3 variant (round-2/4 verified). No x store. r_final =
//        r_pre - A(H) via an H-ring exchange through the LDS tile (ring
//        cells are bit-exact recomputations: contamination depth after 10
//        sweeps is 10 < 15). Block-reduces sum(r^2), sum(f^2) into accp;
//        the LAST block computes the final norm (device-scope counter) ->
//        no finalize dispatch.
// ---------------------------------------------------------------------------
template <bool FIRST, bool RES>
__global__ __launch_bounds__(256) void fused_cycle(
        const float* __restrict__ xin, float* __restrict__ xout,
        const float* __restrict__ f, const float* __restrict__ kernelA,
        const float* __restrict__ lfa,
        const float* __restrict__ W1, const float* __restrict__ b1,
        const float* __restrict__ W2, const float* __restrict__ b2,
        float* __restrict__ accp, float* __restrict__ outp) {
    __shared__ float sxraw[98 * TWP + 2];
    float* sx = sxraw + TWP + 1;   // logical origin (0,0); row r col c -> sx[r*TWP+c]
    const int tx = threadIdx.x;   // 0..31
    const int ty = threadIdx.y;   // 0..7
    const int t  = ty * 32 + tx;
    const int b  = blockIdx.z;
    const int gy0 = blockIdx.y * OT;
    const int gx0 = blockIdx.x * OT;
    const int goi = gy0 - HALO;
    const int goj = gx0 - HALO;
    const float* fg = f + (size_t)b * NN * NN;
    const float* ag = kernelA + b * 9;   // uniform -> s_load
    const float ar0 = ag[0], ar1 = ag[1], ar2 = ag[2], ar3 = ag[3], ar4 = ag[4];
    const float ar5 = ag[5], ar6 = ag[6], ar7 = ag[7], ar8 = ag[8];
    const float tau = 0.5f / ar4;
    // tau-scaled stencil for the sweeps
    const float s0 = tau * ar0, q1 = tau * ar1, q2 = tau * ar2, q3 = tau * ar3;
    const float q4 = tau * ar4, q5 = tau * ar5, q6 = tau * ar6, q7 = tau * ar7;
    const float q8 = tau * ar8;

    if (FIRST) {
        // zero norm accumulators + done-counter (stream order puts this
        // before cycle-3's atomics)
        if (t == 0 && (blockIdx.x | blockIdx.y | blockIdx.z) == 0) {
            accp[0] = 0.f;
            accp[1] = 0.f;
            ((unsigned int*)accp)[2] = 0u;
        }
    }

    // ---- zero the guard ring (top band, shared L/R col guards, bottom band)
    if (t < 98) sxraw[t] = 0.f;                 // logical row -1, col -1..96
    if (t < 96) sxraw[97 + 97 * t] = 0.f;       // col -1 of row t (== col 96 of row t-1)
    if (t < 98) sxraw[9409 + t] = 0.f;          // logical row 96, col -1..96

    // ---- Phase A: tile -> LDS (interior 96x96), float4 strips ----
    if (!FIRST) {
        const float* xg = xin + (size_t)b * NN * NN;
#pragma unroll
        for (int k = 0; k < 9; ++k) {
            int idx = t + k * 256;           // 0..2303 strips
            int row = idx / 24;              // 0..95
            int c4  = (idx - row * 24) * 4;  // 0,4,...,92
            int gi = goi + row, gj = goj + c4;
            float4 v = {0.f, 0.f, 0.f, 0.f};
            if ((unsigned)gi < NN && (unsigned)gj < NN)
                v = *(const float4*)(xg + (size_t)gi * NN + gj);
            float* d = sx + row * TWP + c4;
            d[0] = v.x; d[1] = v.y; d[2] = v.z; d[3] = v.w;
        }
    }

    const int R0 = ty * 12, C0 = tx * 3;

    // single base pointers: all LDS traffic below is base + compile-time imm
    const float* pb  = sx + (R0 - 1) * TWP + (C0 - 1);  // extended-block origin
    float*       pwv = sx + R0 * TWP + C0;              // owned-cell origin

    // masks: cell updates only if tile-interior AND inside global domain
    float vR[12], vC[3];
#pragma unroll
    for (int r = 0; r < 12; ++r) {
        int R = R0 + r, gi = goi + R;
        vR[r] = (R >= 1 && R < TW - 1 && gi >= 0 && gi < NN) ? 1.f : 0.f;
    }
#pragma unroll
    for (int c = 0; c < 3; ++c) {
        int C = C0 + c, gj = goj + C;
        vC[c] = (C >= 1 && C < TW - 1 && gj >= 0 && gj < NN) ? 1.f : 0.f;
    }

    // tau-scaled f for owned cells (0 outside domain)
    float frt[12][3];
#pragma unroll
    for (int r = 0; r < 12; ++r) {
        int gi = goi + R0 + r;
#pragma unroll
        for (int c = 0; c < 3; ++c) {
            int gj = goj + C0 + c;
            frt[r][c] = (gi >= 0 && gi < NN && gj >= 0 && gj < NN)
                            ? tau * fg[gi * NN + gj] : 0.f;
        }
    }

    __syncthreads();   // tile + guards visible

    // ---- Phase B: own cells -> registers ----
    float cur[12][3];
    if (FIRST) {
        // collapsed sweep 0: x1 = mask * (tau*f); publish borders
#pragma unroll
        for (int r = 0; r < 12; ++r) {
#pragma unroll
            for (int c = 0; c < 3; ++c)
                cur[r][c] = (vR[r] * vC[c]) * frt[r][c];
        }
        pwv[0] = cur[0][0]; pwv[1] = cur[0][1]; pwv[2] = cur[0][2];
        pwv[11 * TWP] = cur[11][0]; pwv[11 * TWP + 1] = cur[11][1];
        pwv[11 * TWP + 2] = cur[11][2];
#pragma unroll
        for (int r = 1; r < 11; ++r) {
            pwv[r * TWP] = cur[r][0];
            pwv[r * TWP + 2] = cur[r][2];
        }
        __syncthreads();   // sweep-0 borders visible
    } else {
#pragma unroll
        for (int r = 0; r < 12; ++r) {
            cur[r][0] = pwv[r * TWP];
            cur[r][1] = pwv[r * TWP + 1];
            cur[r][2] = pwv[r * TWP + 2];
        }
    }

    // ---- Phase C: sweeps (FIRST starts at s=1: sweep 0 was collapsed) ----
    for (int s = FIRST ? 1 : 0; s < 10; ++s) {
        // halo reads (34), all immediate offsets off pb
        float top0 = pb[0], top1 = pb[1], top2 = pb[2], top3 = pb[3], top4 = pb[4];
        float bot0 = pb[13 * TWP],     bot1 = pb[13 * TWP + 1],
              bot2 = pb[13 * TWP + 2], bot3 = pb[13 * TWP + 3],
              bot4 = pb[13 * TWP + 4];
        float pm0 = top1, pm1v = top2, pm2 = top3;
        float Lm1 = top0, Rm1 = top4;
        float Lc = pb[TWP], Rc = pb[TWP + 4];
#pragma unroll
        for (int r = 0; r < 12; ++r) {
            float n0, n1, n2, Lp, Rp;
            if (r < 11) {
                n0 = cur[r + 1][0]; n1 = cur[r + 1][1]; n2 = cur[r + 1][2];
                Lp = pb[(r + 2) * TWP];
                Rp = pb[(r + 2) * TWP + 4];
            } else {
                n0 = bot1; n1 = bot2; n2 = bot3; Lp = bot0; Rp = bot4;
            }
            float o0 = cur[r][0], o1 = cur[r][1], o2 = cur[r][2];
            // c = 0
            {
                float ax = s0 * Lm1;
                ax = fmaf(q1, pm0, ax); ax = fmaf(q2, pm1v, ax);
                ax = fmaf(q3, Lc, ax);  ax = fmaf(q4, o0, ax);
                ax = fmaf(q5, o1, ax);  ax = fmaf(q6, Lp, ax);
                ax = fmaf(q7, n0, ax);  ax = fmaf(q8, n1, ax);
                cur[r][0] = fmaf(vR[r] * vC[0], frt[r][0] - ax, o0);
            }
            // c = 1
            {
                float ax = s0 * pm0;
                ax = fmaf(q1, pm1v, ax); ax = fmaf(q2, pm2, ax);
                ax = fmaf(q3, o0, ax);   ax = fmaf(q4, o1, ax);
                ax = fmaf(q5, o2, ax);   ax = fmaf(q6, n0, ax);
                ax = fmaf(q7, n1, ax);   ax = fmaf(q8, n2, ax);
                cur[r][1] = fmaf(vR[r] * vC[1], frt[r][1] - ax, o1);
            }
            // c = 2
            {
                float ax = s0 * pm1v;
                ax = fmaf(q1, pm2, ax); ax = fmaf(q2, Rm1, ax);
                ax = fmaf(q3, o1, ax);  ax = fmaf(q4, o2, ax);
                ax = fmaf(q5, Rc, ax);  ax = fmaf(q6, n1, ax);
                ax = fmaf(q8, Rp, fmaf(q7, n2, ax));
                cur[r][2] = fmaf(vR[r] * vC[2], frt[r][2] - ax, o2);
            }
            pm0 = o0; pm1v = o1; pm2 = o2;
            Lm1 = Lc; Rm1 = Rc; Lc = Lp; Rc = Rp;
        }
        __syncthreads();   // all halo reads done
        if (s < 9) {
            // write border cells (26)
            pwv[0] = cur[0][0]; pwv[1] = cur[0][1]; pwv[2] = cur[0][2];
            pwv[11 * TWP] = cur[11][0]; pwv[11 * TWP + 1] = cur[11][1];
            pwv[11 * TWP + 2] = cur[11][2];
#pragma unroll
            for (int r = 1; r < 11; ++r) {
                pwv[r * TWP] = cur[r][0];
                pwv[r * TWP + 2] = cur[r][2];
            }
        } else {
            // final sweep: publish ALL cells for the correction phase
#pragma unroll
            for (int r = 0; r < 12; ++r) {
                pwv[r * TWP] = cur[r][0];
                pwv[r * TWP + 1] = cur[r][1];
                pwv[r * TWP + 2] = cur[r][2];
            }
        }
        __syncthreads();   // writes visible
    }

    // ---- Phase D: remapped correction, exactly 1x MLP work ----
    // thread t -> output row orow = t/4 (0..63), column segment oseg = t%4
    // Pitch 97: bank = orow + 16*oseg + k + const (mod 32) -> 2 lanes/bank (free).
    const int orow = t >> 2;
    const int oseg = t & 3;
    const int Rl = HALO + orow;           // 16..79
    const int Cl0 = HALO + oseg * 16;     // 16,32,48,64
    const float* pw = sx + (Rl - 1) * TWP + (Cl0 - 1);   // single base + imm
    const int gi = gy0 + orow;
    const int gjb = gx0 + oseg * 16;
    const float b2v = b2[0];

    if (!RES) {
        // ---- round-0-proven path (128 VGPR): bulk w loads, output store ----
        float w0[18], w1[18], w2[18];
#pragma unroll
        for (int k = 0; k < 18; ++k) {
            w0[k] = pw[k];
            w1[k] = pw[TWP + k];
            w2[k] = pw[2 * TWP + k];
        }
        const float4* f4 = (const float4*)(fg + (size_t)gi * NN + gjb);
        const float4* l4 = (const float4*)(lfa + (size_t)b * NN * NN + (size_t)gi * NN + gjb);
        float fv[16], lv[16];
#pragma unroll
        for (int q = 0; q < 4; ++q) {
            float4 fq = f4[q], lq = l4[q];
            fv[q * 4] = fq.x; fv[q * 4 + 1] = fq.y; fv[q * 4 + 2] = fq.z; fv[q * 4 + 3] = fq.w;
            lv[q * 4] = lq.x; lv[q * 4 + 1] = lq.y; lv[q * 4 + 2] = lq.z; lv[q * 4 + 3] = lq.w;
        }
        float rv[16];
#pragma unroll
        for (int k = 0; k < 16; ++k) {
            float ax = ar0 * w0[k];
            ax = fmaf(ar1, w0[k + 1], ax); ax = fmaf(ar2, w0[k + 2], ax);
            ax = fmaf(ar3, w1[k], ax);     ax = fmaf(ar4, w1[k + 1], ax);
            ax = fmaf(ar5, w1[k + 2], ax); ax = fmaf(ar6, w2[k], ax);
            ax = fmaf(ar7, w2[k + 1], ax); ax = fmaf(ar8, w2[k + 2], ax);
            rv[k] = fv[k] - ax;
        }
        float acc[16];
#pragma unroll
        for (int k = 0; k < 16; ++k) acc[k] = 0.f;
        for (int hh = 0; hh < HID; ++hh) {
            float w1a = W1[2 * hh], w1b = W1[2 * hh + 1], bb = b1[hh], wo = W2[hh];
#pragma unroll
            for (int k = 0; k < 16; ++k) {
                float v = fmaf(w1a, lv[k], fmaf(w1b, rv[k], bb));
                float m = v * fmaf(GELU_K2, v * v, GELU_K1);
                float e = __builtin_amdgcn_exp2f(m);
                float g = v * __builtin_amdgcn_rcpf(1.0f + e);
                acc[k] = fmaf(wo, g, acc[k]);
            }
        }
        float4* xo4 = (float4*)(xout + (size_t)b * NN * NN + (size_t)gi * NN + gjb);
#pragma unroll
        for (int q = 0; q < 4; ++q) {
            float4 ov;
            ov.x = w1[q * 4 + 1] + acc[q * 4] + b2v;
            ov.y = w1[q * 4 + 2] + acc[q * 4 + 1] + b2v;
            ov.z = w1[q * 4 + 3] + acc[q * 4 + 2] + b2v;
            ov.w = w1[q * 4 + 4] + acc[q * 4 + 3] + b2v;
            xo4[q] = ov;
        }
    } else {
        // ---- round-2/4-verified register-light residual path ----
        // r_pre = f - A(w), row-by-row so only 18 w values are live at once
        float rv[16];
        {
            float w[18];
#pragma unroll
            for (int k = 0; k < 18; ++k) w[k] = pw[k];
#pragma unroll
            for (int k = 0; k < 16; ++k) {
                float ax = ar0 * w[k];
                ax = fmaf(ar1, w[k + 1], ax);
                rv[k] = fmaf(ar2, w[k + 2], ax);
            }
#pragma unroll
            for (int k = 0; k < 18; ++k) w[k] = pw[TWP + k];
#pragma unroll
            for (int k = 0; k < 16; ++k) {
                float ax = fmaf(ar3, w[k], rv[k]);
                ax = fmaf(ar4, w[k + 1], ax);
                rv[k] = fmaf(ar5, w[k + 2], ax);
            }
#pragma unroll
            for (int k = 0; k < 18; ++k) w[k] = pw[2 * TWP + k];
#pragma unroll
            for (int k = 0; k < 16; ++k) {
                float ax = fmaf(ar6, w[k], rv[k]);
                ax = fmaf(ar7, w[k + 1], ax);
                rv[k] = fmaf(ar8, w[k + 2], ax);
            }
        }
        float f2 = 0.f;
        {
            const float4* f4 = (const float4*)(fg + (size_t)gi * NN + gjb);
#pragma unroll
            for (int q = 0; q < 4; ++q) {
                float4 fq = f4[q];
                rv[q * 4]     = fq.x - rv[q * 4];
                rv[q * 4 + 1] = fq.y - rv[q * 4 + 1];
                rv[q * 4 + 2] = fq.z - rv[q * 4 + 2];
                rv[q * 4 + 3] = fq.w - rv[q * 4 + 3];
                f2 = fmaf(fq.x, fq.x, f2);
                f2 = fmaf(fq.y, fq.y, f2);
                f2 = fmaf(fq.z, fq.z, f2);
                f2 = fmaf(fq.w, fq.w, f2);
            }
        }

        // ---- ring-cell H: the 66x66 frame around the 64x64 output region.
        // Ring cells are >= 11 cells from the tile rim -> their sweep values
        // (and therefore H) are bit-identical to the neighbor block's own
        // computation. 260 cells: every thread takes one, threads 0..3 take 2.
        // Runs while only rv[16] + f2 are live. LFA read from the buffer.
        float Hr0 = 0.f, Hr1 = 0.f;
        int hoff0 = 0, hoff1 = 0;
        auto ringH = [&](int rc, float& Hv, int& hoff) {
            int R, C;
            if (rc < 66)       { R = 15; C = 15 + rc; }
            else if (rc < 132) { R = 80; C = rc - 51; }
            else if (rc < 196) { R = rc - 116; C = 15; }
            else               { R = rc - 180; C = 80; }
            hoff = R * TWP + C;
            int rgi = goi + R, rgj = goj + C;
            Hv = 0.f;
            if (rgi >= 0 && rgi < NN && rgj >= 0 && rgj < NN) {
                const float* pr = sx + (R - 1) * TWP + (C - 1);
                float u0 = pr[0], u1 = pr[1], u2 = pr[2];
                float m0 = pr[TWP], m1 = pr[TWP + 1], m2 = pr[TWP + 2];
                float d0 = pr[2 * TWP], d1 = pr[2 * TWP + 1], d2 = pr[2 * TWP + 2];
                float ax = ar0 * u0;
                ax = fmaf(ar1, u1, ax); ax = fmaf(ar2, u2, ax);
                ax = fmaf(ar3, m0, ax); ax = fmaf(ar4, m1, ax);
                ax = fmaf(ar5, m2, ax); ax = fmaf(ar6, d0, ax);
                ax = fmaf(ar7, d1, ax); ax = fmaf(ar8, d2, ax);
                float rp = fg[(size_t)rgi * NN + rgj] - ax;
                float lf = lfa[(size_t)b * NN * NN + (size_t)rgi * NN + rgj];
                float av = 0.f;
                for (int hh = 0; hh < HID; ++hh) {
                    float w1a = W1[2 * hh], w1b = W1[2 * hh + 1], bbv = b1[hh], wo = W2[hh];
                    float v = fmaf(w1a, lf, fmaf(w1b, rp, bbv));
                    float m = v * fmaf(GELU_K2, v * v, GELU_K1);
                    float e = __builtin_amdgcn_exp2f(m);
                    float gg = v * __builtin_amdgcn_rcpf(1.0f + e);
                    av = fmaf(wo, gg, av);
                }
                Hv = av + b2v;
            }
        };
        ringH(t, Hr0, hoff0);
        if (t < 4) ringH(t + 256, Hr1, hoff1);

        // ---- own-cell MLP: lv loaded just-in-time ----
        float acc[16];
#pragma unroll
        for (int k = 0; k < 16; ++k) acc[k] = 0.f;
        {
            float lv[16];
            const float4* l4 = (const float4*)(lfa + (size_t)b * NN * NN + (size_t)gi * NN + gjb);
#pragma unroll
            for (int q = 0; q < 4; ++q) {
                float4 lq = l4[q];
                lv[q * 4] = lq.x; lv[q * 4 + 1] = lq.y;
                lv[q * 4 + 2] = lq.z; lv[q * 4 + 3] = lq.w;
            }
            for (int hh = 0; hh < HID; ++hh) {
                float w1a = W1[2 * hh], w1b = W1[2 * hh + 1], bb = b1[hh], wo = W2[hh];
#pragma unroll
                for (int k = 0; k < 16; ++k) {
                    float v = fmaf(w1a, lv[k], fmaf(w1b, rv[k], bb));
                    float m = v * fmaf(GELU_K2, v * v, GELU_K1);
                    float e = __builtin_amdgcn_exp2f(m);
                    float g = v * __builtin_amdgcn_rcpf(1.0f + e);
                    acc[k] = fmaf(wo, g, acc[k]);
                }
            }
        }

        __syncthreads();   // all LDS w-reads (own + ring) complete
        // publish H on [15,81)^2 in place over the sweep tile
        float* ph = sx + Rl * TWP + Cl0;
#pragma unroll
        for (int k = 0; k < 16; ++k) ph[k] = acc[k] + b2v;
        sx[hoff0] = Hr0;
        if (t < 4) sx[hoff1] = Hr1;
        __syncthreads();   // H tile visible

        // r_final = r_pre - A(H), row-by-row to keep live range small
        float rr = 0.f;
        {
            float hr[18];
#pragma unroll
            for (int k = 0; k < 18; ++k) hr[k] = pw[k];
#pragma unroll
            for (int k = 0; k < 16; ++k) {
                float ax = ar0 * hr[k];
                ax = fmaf(ar1, hr[k + 1], ax);
                ax = fmaf(ar2, hr[k + 2], ax);
                rv[k] -= ax;
            }
#pragma unroll
            for (int k = 0; k < 18; ++k) hr[k] = pw[TWP + k];
#pragma unroll
            for (int k = 0; k < 16; ++k) {
                float ax = ar3 * hr[k];
                ax = fmaf(ar4, hr[k + 1], ax);
                ax = fmaf(ar5, hr[k + 2], ax);
                rv[k] -= ax;
            }
#pragma unroll
            for (int k = 0; k < 18; ++k) hr[k] = pw[2 * TWP + k];
#pragma unroll
            for (int k = 0; k < 16; ++k) {
                float ax = ar6 * hr[k];
                ax = fmaf(ar7, hr[k + 1], ax);
                ax = fmaf(ar8, hr[k + 2], ax);
                float r = rv[k] - ax;
                rr = fmaf(r, r, rr);
            }
        }
        // block reduction -> one atomicAdd pair; LAST block finalizes
#pragma unroll
        for (int off = 32; off > 0; off >>= 1) {
            rr += __shfl_down(rr, off, 64);
            f2 += __shfl_down(f2, off, 64);
        }
        if ((t & 63) == 0) { sxraw[t >> 6] = rr; sxraw[4 + (t >> 6)] = f2; }
        __syncthreads();
        if (t == 0) {
            atomicAdd(&accp[0], sxraw[0] + sxraw[1] + sxraw[2] + sxraw[3]);
            atomicAdd(&accp[1], sxraw[4] + sxraw[5] + sxraw[6] + sxraw[7]);
            __threadfence();
            unsigned int done = atomicAdd((unsigned int*)accp + 2, 1u);
            if (done == (NN / OT) * (NN / OT) * BB - 1) {
                __threadfence();
                float rrt = atomicAdd(&accp[0], 0.f);   // coherent (L2) read
                float fft = atomicAdd(&accp[1], 0.f);
                outp[0] = sqrtf(rrt / fft);
            }
        }
    }
}

// ---------------------------------------------------------------------------
extern "C" void kernel_launch(void* const* d_in, const int* in_sizes, int n_in,
                              void* d_out, int out_size, void* d_ws, size_t ws_size,
                              hipStream_t stream) {
    const float* f  = (const float*)d_in[0];
    const float* kA = (const float*)d_in[1];
    float*       u  = (float*)d_in[2];   // scratch (fully overwritten by cycle 2)
    const float* W1 = (const float*)d_in[3];
    const float* b1 = (const float*)d_in[4];
    const float* W2 = (const float*)d_in[5];
    const float* b2 = (const float*)d_in[6];
    float* out = (float*)d_out;

    char* ws = (char*)d_ws;
    float* acc = (float*)ws;                                     // 12 B
    float* xB  = (float*)(ws + 256);                             // 16 MiB
    float* lfa = (float*)(ws + 256 + (size_t)BB * NN * NN * 4);  // 16 MiB

    lfa_kernel<<<dim3(1, NN / 2, BB), 256, 0, stream>>>(kA, lfa);

    dim3 jblk(32, 8);
    dim3 jgrd(NN / OT, NN / OT, BB);

    // cycle 1 (x = 0, collapsed sweep 0; zeroes acc), cycle 2,
    // cycle 3 (fused residual norm + last-block finalize, no x store)
    fused_cycle<true,  false><<<jgrd, jblk, 0, stream>>>(u, xB, f, kA, lfa, W1, b1, W2, b2, acc, out);
    fused_cycle<false, false><<<jgrd, jblk, 0, stream>>>(xB, u, f, kA, lfa, W1, b1, W2, b2, acc, out);
    fused_cycle<false, true ><<<jgrd, jblk, 0, stream>>>(u, xB, f, kA, lfa, W1, b1, W2, b2, acc, out);
}